// Round 3
// baseline (1334.189 us; speedup 1.0000x reference)
//
#include <hip/hip_runtime.h>

// GLM MLA fused pipeline, round 2 (baseline resubmit — GPU never acquired; 2nd audit clean).
// Stages: f32->f16 convert; weight transpose-convert (B^T layout, rope cols
// dropped); QKV GEMM (m97 128x128/BK=32 global_load_lds structure) with
// layout-scattering epilogue (Q,K -> [B,H,S,128], V -> [B,H,128,S] transposed);
// causal flash attention (4 waves x 16 q-rows, KVBLK=64, LDS P-bounce);
// output GEMM -> fp32 d_out.
// Workspace peak: 224 MiB (wo^T aliases hs16, attn aliases wqkvT).

typedef __attribute__((ext_vector_type(4))) float f32x4;
typedef _Float16 half8 __attribute__((ext_vector_type(8)));
typedef _Float16 half4 __attribute__((ext_vector_type(4)));

#define AS3(p) ((__attribute__((address_space(3))) void*)(p))
#define AS1(p) ((__attribute__((address_space(1))) void*)(void*)(p))

// ---------------- hs f32 -> f16 ----------------
__global__ __launch_bounds__(256) void k_convert(const float* __restrict__ src,
                                                 _Float16* __restrict__ dst) {
  int i = (blockIdx.x * 256 + threadIdx.x) * 8;
  float4 a = *(const float4*)(src + i);
  float4 b = *(const float4*)(src + i + 4);
  half8 v = { (_Float16)a.x, (_Float16)a.y, (_Float16)a.z, (_Float16)a.w,
              (_Float16)b.x, (_Float16)b.y, (_Float16)b.z, (_Float16)b.w };
  *(half8*)(dst + i) = v;
}

// ------- transpose-convert wq(nope cols)+wkv -> wqkvT [12288][4096] f16 -------
// out[c][r]: c<4096 -> wq[r][(c>>7)*192 + (c&127)] ; else wkv[r][c-4096]
__global__ __launch_bounds__(256) void k_tc_qkv(const float* __restrict__ wq,
                                                const float* __restrict__ wkv,
                                                _Float16* __restrict__ out) {
  __shared__ __align__(16) _Float16 t[64][72];
  int k0 = blockIdx.x * 64;
  int c0 = blockIdx.y * 64;
  int tid = threadIdx.x;
  int rl = tid >> 4;
  int cl4 = (tid & 15) << 2;
  int c = c0 + cl4;
#pragma unroll
  for (int i = 0; i < 4; ++i) {
    int r = k0 + rl + i * 16;
    const float* sp;
    if (c0 < 4096) sp = wq + (size_t)r * 6144 + ((c >> 7) * 192 + (c & 127));
    else           sp = wkv + (size_t)r * 8256 + (c - 4096);
    float4 v = *(const float4*)sp;
    t[cl4 + 0][rl + i * 16] = (_Float16)v.x;
    t[cl4 + 1][rl + i * 16] = (_Float16)v.y;
    t[cl4 + 2][rl + i * 16] = (_Float16)v.z;
    t[cl4 + 3][rl + i * 16] = (_Float16)v.w;
  }
  __syncthreads();
  int r4 = (tid & 15) << 2;
#pragma unroll
  for (int i = 0; i < 4; ++i) {
    int cl = (tid >> 4) + i * 16;
    half4 p = { t[cl][r4], t[cl][r4 + 1], t[cl][r4 + 2], t[cl][r4 + 3] };
    *(half4*)(out + (size_t)(c0 + cl) * 4096 + k0 + r4) = p;
  }
}

// ------- transpose-convert wo -> woT [4096][4096] f16 -------
__global__ __launch_bounds__(256) void k_tc_wo(const float* __restrict__ wo,
                                               _Float16* __restrict__ out) {
  __shared__ __align__(16) _Float16 t[64][72];
  int k0 = blockIdx.x * 64;
  int c0 = blockIdx.y * 64;
  int tid = threadIdx.x;
  int rl = tid >> 4;
  int cl4 = (tid & 15) << 2;
#pragma unroll
  for (int i = 0; i < 4; ++i) {
    int r = k0 + rl + i * 16;
    float4 v = *(const float4*)(wo + (size_t)r * 4096 + c0 + cl4);
    t[cl4 + 0][rl + i * 16] = (_Float16)v.x;
    t[cl4 + 1][rl + i * 16] = (_Float16)v.y;
    t[cl4 + 2][rl + i * 16] = (_Float16)v.z;
    t[cl4 + 3][rl + i * 16] = (_Float16)v.w;
  }
  __syncthreads();
  int r4 = (tid & 15) << 2;
#pragma unroll
  for (int i = 0; i < 4; ++i) {
    int cl = (tid >> 4) + i * 16;
    half4 p = { t[cl][r4], t[cl][r4 + 1], t[cl][r4 + 2], t[cl][r4 + 3] };
    *(half4*)(out + (size_t)(c0 + cl) * 4096 + k0 + r4) = p;
  }
}

// ---------------- GEMM: C = A[M][K] * Bt[N][K]^T, m97 structure ----------------
// mode 1: QKV epilogue (outp = Q base; K = Q+16Mi elems; Vt = Q+32Mi elems)
// mode 2: fp32 row-major [M][N] epilogue
__global__ __launch_bounds__(256) void k_gemm(const _Float16* __restrict__ A,
                                              const _Float16* __restrict__ Bt,
                                              void* __restrict__ outp,
                                              int M, int N, int K, int mode) {
  __shared__ __align__(16) _Float16 sA[128 * 32];
  __shared__ __align__(16) _Float16 sB[128 * 32];
  int tid = threadIdx.x;
  int lane = tid & 63;
  int wave = tid >> 6;
  int m0 = blockIdx.y * 128;
  int n0 = blockIdx.x * 128;
  int wr = wave >> 1, wc = wave & 1;

  f32x4 acc[4][4];
#pragma unroll
  for (int i = 0; i < 4; ++i)
#pragma unroll
    for (int j = 0; j < 4; ++j) acc[i][j] = (f32x4){0.f, 0.f, 0.f, 0.f};

  const char* Ab = (const char*)(A + (size_t)m0 * K);
  const char* Bb = (const char*)(Bt + (size_t)n0 * K);
  int c0 = wave * 2, c1 = wave * 2 + 1;
  // chunk c: rows c*16 + lane/4, 16B piece (lane&3) within the 64B row
  size_t off0 = ((size_t)(c0 * 16 + (lane >> 2)) * K) * 2 + (size_t)(lane & 3) * 16;
  size_t off1 = ((size_t)(c1 * 16 + (lane >> 2)) * K) * 2 + (size_t)(lane & 3) * 16;

  for (int kt = 0; kt < K; kt += 32) {
    size_t kb = (size_t)kt * 2;
    __builtin_amdgcn_global_load_lds(AS1(Ab + off0 + kb), AS3((char*)sA + c0 * 1024), 16, 0, 0);
    __builtin_amdgcn_global_load_lds(AS1(Ab + off1 + kb), AS3((char*)sA + c1 * 1024), 16, 0, 0);
    __builtin_amdgcn_global_load_lds(AS1(Bb + off0 + kb), AS3((char*)sB + c0 * 1024), 16, 0, 0);
    __builtin_amdgcn_global_load_lds(AS1(Bb + off1 + kb), AS3((char*)sB + c1 * 1024), 16, 0, 0);
    __syncthreads();
    const _Float16* pa = sA + (wr * 64 + (lane & 15)) * 32 + ((lane >> 4) << 3);
    const _Float16* pb = sB + (wc * 64 + (lane & 15)) * 32 + ((lane >> 4) << 3);
    half8 af[4], bfr[4];
#pragma unroll
    for (int mi = 0; mi < 4; ++mi) af[mi] = *(const half8*)(pa + mi * 16 * 32);
#pragma unroll
    for (int ni = 0; ni < 4; ++ni) bfr[ni] = *(const half8*)(pb + ni * 16 * 32);
#pragma unroll
    for (int mi = 0; mi < 4; ++mi)
#pragma unroll
      for (int ni = 0; ni < 4; ++ni)
        acc[mi][ni] = __builtin_amdgcn_mfma_f32_16x16x32_f16(af[mi], bfr[ni], acc[mi][ni], 0, 0, 0);
    __syncthreads();
  }

  int rowb = m0 + wr * 64 + ((lane >> 4) << 2);
  if (mode == 2) {
    float* O = (float*)outp;
#pragma unroll
    for (int mi = 0; mi < 4; ++mi)
#pragma unroll
      for (int j = 0; j < 4; ++j) {
        size_t r = (size_t)(rowb + mi * 16 + j);
        float* op = O + r * N + n0 + wc * 64 + (lane & 15);
#pragma unroll
        for (int ni = 0; ni < 4; ++ni) op[ni * 16] = acc[mi][ni][j];
      }
  } else {
    _Float16* Q = (_Float16*)outp;
    _Float16* Kk = Q + 16777216;   // +32 MiB
    _Float16* Vt = Q + 33554432;   // +64 MiB
    int seg = n0 >> 12;            // 0:q 1:k 2:v
    int h = (n0 >> 7) & 31;
    if (seg < 2) {
      _Float16* Obuf = (seg == 0) ? Q : Kk;
#pragma unroll
      for (int mi = 0; mi < 4; ++mi) {
        int t0 = rowb + mi * 16;
        int bb = t0 >> 10, s0 = t0 & 1023;
        size_t base = ((size_t)bb * 32 + h) * 1024;
#pragma unroll
        for (int j = 0; j < 4; ++j)
#pragma unroll
          for (int ni = 0; ni < 4; ++ni)
            Obuf[(base + s0 + j) * 128 + wc * 64 + ni * 16 + (lane & 15)] =
                (_Float16)acc[mi][ni][j];
      }
    } else {
#pragma unroll
      for (int mi = 0; mi < 4; ++mi) {
        int t0 = rowb + mi * 16;
        int bb = t0 >> 10, s0 = t0 & 1023;
#pragma unroll
        for (int ni = 0; ni < 4; ++ni) {
          int d = wc * 64 + ni * 16 + (lane & 15);
          half4 p = { (_Float16)acc[mi][ni][0], (_Float16)acc[mi][ni][1],
                      (_Float16)acc[mi][ni][2], (_Float16)acc[mi][ni][3] };
          *(half4*)(Vt + (((size_t)bb * 32 + h) * 128 + d) * 1024 + s0) = p;
        }
      }
    }
  }
}

// ---------------- causal flash attention ----------------
// Q,K: [B,H,S,128] f16 ; Vt: [B,H,128,S] f16 ; out: [B*S][H*128] f16
__global__ __launch_bounds__(256) void k_attn(const _Float16* __restrict__ Qb,
                                              const _Float16* __restrict__ Kb,
                                              const _Float16* __restrict__ Vtb,
                                              _Float16* __restrict__ outp) {
  __shared__ __align__(16) _Float16 sK[64][152];     // [kv][d] pad->2-way banks
  __shared__ __align__(16) _Float16 sV[128][72];     // [d][kv]
  __shared__ __align__(16) _Float16 sP[4][16][72];   // per wave [q][kv]
  const float SCL = 0.10411834905624762f;  // 192^-0.5 * log2(e)
  int tid = threadIdx.x;
  int lane = tid & 63;
  int w = tid >> 6;
  int qt = blockIdx.x;
  int h = blockIdx.y;
  int b = blockIdx.z;
  int q0 = qt * 64;
  size_t bh = (size_t)b * 32 + h;
  const _Float16* Qp = Qb + bh * (1024 * 128);
  const _Float16* Kp = Kb + bh * (1024 * 128);
  const _Float16* Vp = Vtb + bh * (128 * 1024);

  half8 aQ[4];
  {
    const _Float16* qr = Qp + (size_t)(q0 + w * 16 + (lane & 15)) * 128 + ((lane >> 4) << 3);
#pragma unroll
    for (int ks = 0; ks < 4; ++ks) aQ[ks] = *(const half8*)(qr + ks * 32);
  }
  f32x4 accO[8];
#pragma unroll
  for (int g = 0; g < 8; ++g) accO[g] = (f32x4){0.f, 0.f, 0.f, 0.f};
  float m_r[4] = { -__builtin_inff(), -__builtin_inff(), -__builtin_inff(), -__builtin_inff() };
  float l_r[4] = { 0.f, 0.f, 0.f, 0.f };

  int ntile = qt + 1;
  int qrb = q0 + w * 16 + ((lane >> 4) << 2);
  for (int kt = 0; kt < ntile; ++kt) {
    int kv0 = kt * 64;
    // stage K tile [64][128]: 1024 x 16B
#pragma unroll
    for (int i = 0; i < 4; ++i) {
      int idx = tid + i * 256;
      int r = idx >> 4;
      int cb = (idx & 15) << 3;
      *(int4*)&sK[r][cb] = *(const int4*)(Kp + (size_t)(kv0 + r) * 128 + cb);
    }
    // stage Vt tile [128][64]
#pragma unroll
    for (int i = 0; i < 4; ++i) {
      int idx = tid + i * 256;
      int r = idx >> 3;
      int cb = (idx & 7) << 3;
      *(int4*)&sV[r][cb] = *(const int4*)(Vp + (size_t)r * 1024 + kv0 + cb);
    }
    __syncthreads();
    // QK^T : per wave 16 q-rows x 64 kv
    f32x4 sc[4];
#pragma unroll
    for (int g = 0; g < 4; ++g) {
      f32x4 c = (f32x4){0.f, 0.f, 0.f, 0.f};
#pragma unroll
      for (int ks = 0; ks < 4; ++ks) {
        half8 bk = *(const half8*)&sK[g * 16 + (lane & 15)][ks * 32 + ((lane >> 4) << 3)];
        c = __builtin_amdgcn_mfma_f32_16x16x32_f16(aQ[ks], bk, c, 0, 0, 0);
      }
      sc[g] = c;
    }
    // mask + online softmax (log2 domain)
    bool diag = (kt == ntile - 1);
    float sv[4][4];  // [j][g]
#pragma unroll
    for (int g = 0; g < 4; ++g) {
      int kvc = kv0 + g * 16 + (lane & 15);
#pragma unroll
      for (int j = 0; j < 4; ++j) {
        float s = sc[g][j] * SCL;
        if (diag && kvc > qrb + j) s = -__builtin_inff();
        sv[j][g] = s;
      }
    }
#pragma unroll
    for (int j = 0; j < 4; ++j) {
      float mx = fmaxf(fmaxf(sv[j][0], sv[j][1]), fmaxf(sv[j][2], sv[j][3]));
      mx = fmaxf(mx, __shfl_xor(mx, 1));
      mx = fmaxf(mx, __shfl_xor(mx, 2));
      mx = fmaxf(mx, __shfl_xor(mx, 4));
      mx = fmaxf(mx, __shfl_xor(mx, 8));
      float mnew = fmaxf(m_r[j], mx);
      float corr = exp2f(m_r[j] - mnew);
      m_r[j] = mnew;
      float rs = 0.f;
#pragma unroll
      for (int g = 0; g < 4; ++g) {
        float p = exp2f(sv[j][g] - mnew);
        sv[j][g] = p;
        rs += p;
      }
      rs += __shfl_xor(rs, 1);
      rs += __shfl_xor(rs, 2);
      rs += __shfl_xor(rs, 4);
      rs += __shfl_xor(rs, 8);
      l_r[j] = l_r[j] * corr + rs;
#pragma unroll
      for (int g2 = 0; g2 < 8; ++g2) accO[g2][j] *= corr;
    }
    // P -> LDS (re-fragment for A-operand)
#pragma unroll
    for (int j = 0; j < 4; ++j)
#pragma unroll
      for (int g = 0; g < 4; ++g)
        sP[w][((lane >> 4) << 2) + j][g * 16 + (lane & 15)] = (_Float16)sv[j][g];
    __syncthreads();
    // PV : O[16 q][128 dv] += P[16][64] * V[64][128]
#pragma unroll
    for (int ks = 0; ks < 2; ++ks) {
      half8 ap = *(const half8*)&sP[w][lane & 15][ks * 32 + ((lane >> 4) << 3)];
#pragma unroll
      for (int g2 = 0; g2 < 8; ++g2) {
        half8 bv = *(const half8*)&sV[g2 * 16 + (lane & 15)][ks * 32 + ((lane >> 4) << 3)];
        accO[g2] = __builtin_amdgcn_mfma_f32_16x16x32_f16(ap, bv, accO[g2], 0, 0, 0);
      }
    }
    __syncthreads();
  }
  float inv[4];
#pragma unroll
  for (int j = 0; j < 4; ++j) inv[j] = 1.f / l_r[j];
#pragma unroll
  for (int j = 0; j < 4; ++j) {
    size_t rb = ((size_t)b * 1024 + qrb + j) * 4096 + (size_t)h * 128 + (lane & 15);
#pragma unroll
    for (int g2 = 0; g2 < 8; ++g2)
      outp[rb + g2 * 16] = (_Float16)(accO[g2][j] * inv[j]);
  }
}

// ---------------- launch ----------------
extern "C" void kernel_launch(void* const* d_in, const int* in_sizes, int n_in,
                              void* d_out, int out_size, void* d_ws, size_t ws_size,
                              hipStream_t stream) {
  const float* hs  = (const float*)d_in[0];
  const float* wq  = (const float*)d_in[1];
  const float* wkv = (const float*)d_in[2];
  const float* wo  = (const float*)d_in[3];
  char* ws = (char*)d_ws;

  const size_t OFF_HS    = 0;           // 32 MiB (later aliased by woT)
  const size_t OFF_WQKVT = 33554432;    // 96 MiB (later aliased by attn out)
  const size_t OFF_Q     = 134217728;   // 96 MiB (Q | K | Vt)
  const size_t OFF_ATTN  = OFF_WQKVT;
  const size_t OFF_WOT   = OFF_HS;

  _Float16* hs16   = (_Float16*)(ws + OFF_HS);
  _Float16* wqkvT  = (_Float16*)(ws + OFF_WQKVT);
  _Float16* qkv    = (_Float16*)(ws + OFF_Q);
  _Float16* attn   = (_Float16*)(ws + OFF_ATTN);
  _Float16* woT    = (_Float16*)(ws + OFF_WOT);

  // 1) hs -> f16
  k_convert<<<8192, 256, 0, stream>>>(hs, hs16);
  // 2) weights -> B^T f16 (rope columns dropped)
  k_tc_qkv<<<dim3(64, 192), 256, 0, stream>>>(wq, wkv, wqkvT);
  // 3) QKV projection GEMM, epilogue scatters Q/K/[V^T]
  k_gemm<<<dim3(96, 32), 256, 0, stream>>>(hs16, wqkvT, (void*)qkv, 4096, 12288, 4096, 1);
  // 4) wo -> B^T f16 (hs16 slot is dead now)
  k_tc_wo<<<dim3(64, 64), 256, 0, stream>>>(wo, woT);
  // 5) causal flash attention -> attn [t][4096] f16 (wqkvT slot is dead now)
  k_attn<<<dim3(16, 32, 4), 256, 0, stream>>>(qkv, qkv + 16777216, qkv + 33554432, attn);
  // 6) output projection -> fp32 d_out
  k_gemm<<<dim3(32, 32), 256, 0, stream>>>(attn, woT, d_out, 4096, 4096, 4096, 2);
}

// Round 4
// 1087.585 us; speedup vs baseline: 1.2267x; 1.2267x over previous
//
#include <hip/hip_runtime.h>

// GLM MLA fused pipeline, round 4.
// GEMMs ported to the 256^2 / BK=64 / 8-wave / 8-phase counted-vmcnt template
// (T1 XCD swizzle + T2 slot-XOR LDS swizzle + T3/T4 phases + T5 setprio).
// Attention and converts unchanged from the validated r3 baseline.

typedef __attribute__((ext_vector_type(4))) float f32x4;
typedef _Float16 half8 __attribute__((ext_vector_type(8)));
typedef _Float16 half4 __attribute__((ext_vector_type(4)));

#define AS3(p) ((__attribute__((address_space(3))) void*)(p))
#define AS1(p) ((__attribute__((address_space(1))) void*)(void*)(p))

// ---------------- hs f32 -> f16 ----------------
__global__ __launch_bounds__(256) void k_convert(const float* __restrict__ src,
                                                 _Float16* __restrict__ dst) {
  int i = (blockIdx.x * 256 + threadIdx.x) * 8;
  float4 a = *(const float4*)(src + i);
  float4 b = *(const float4*)(src + i + 4);
  half8 v = { (_Float16)a.x, (_Float16)a.y, (_Float16)a.z, (_Float16)a.w,
              (_Float16)b.x, (_Float16)b.y, (_Float16)b.z, (_Float16)b.w };
  *(half8*)(dst + i) = v;
}

// ------- transpose-convert wq(nope cols)+wkv -> wqkvT [12288][4096] f16 -------
__global__ __launch_bounds__(256) void k_tc_qkv(const float* __restrict__ wq,
                                                const float* __restrict__ wkv,
                                                _Float16* __restrict__ out) {
  __shared__ __align__(16) _Float16 t[64][72];
  int k0 = blockIdx.x * 64;
  int c0 = blockIdx.y * 64;
  int tid = threadIdx.x;
  int rl = tid >> 4;
  int cl4 = (tid & 15) << 2;
  int c = c0 + cl4;
#pragma unroll
  for (int i = 0; i < 4; ++i) {
    int r = k0 + rl + i * 16;
    const float* sp;
    if (c0 < 4096) sp = wq + (size_t)r * 6144 + ((c >> 7) * 192 + (c & 127));
    else           sp = wkv + (size_t)r * 8256 + (c - 4096);
    float4 v = *(const float4*)sp;
    t[cl4 + 0][rl + i * 16] = (_Float16)v.x;
    t[cl4 + 1][rl + i * 16] = (_Float16)v.y;
    t[cl4 + 2][rl + i * 16] = (_Float16)v.z;
    t[cl4 + 3][rl + i * 16] = (_Float16)v.w;
  }
  __syncthreads();
  int r4 = (tid & 15) << 2;
#pragma unroll
  for (int i = 0; i < 4; ++i) {
    int cl = (tid >> 4) + i * 16;
    half4 p = { t[cl][r4], t[cl][r4 + 1], t[cl][r4 + 2], t[cl][r4 + 3] };
    *(half4*)(out + (size_t)(c0 + cl) * 4096 + k0 + r4) = p;
  }
}

// ------- transpose-convert wo -> woT [4096][4096] f16 -------
__global__ __launch_bounds__(256) void k_tc_wo(const float* __restrict__ wo,
                                               _Float16* __restrict__ out) {
  __shared__ __align__(16) _Float16 t[64][72];
  int k0 = blockIdx.x * 64;
  int c0 = blockIdx.y * 64;
  int tid = threadIdx.x;
  int rl = tid >> 4;
  int cl4 = (tid & 15) << 2;
#pragma unroll
  for (int i = 0; i < 4; ++i) {
    int r = k0 + rl + i * 16;
    float4 v = *(const float4*)(wo + (size_t)r * 4096 + c0 + cl4);
    t[cl4 + 0][rl + i * 16] = (_Float16)v.x;
    t[cl4 + 1][rl + i * 16] = (_Float16)v.y;
    t[cl4 + 2][rl + i * 16] = (_Float16)v.z;
    t[cl4 + 3][rl + i * 16] = (_Float16)v.w;
  }
  __syncthreads();
  int r4 = (tid & 15) << 2;
#pragma unroll
  for (int i = 0; i < 4; ++i) {
    int cl = (tid >> 4) + i * 16;
    half4 p = { t[cl][r4], t[cl][r4 + 1], t[cl][r4 + 2], t[cl][r4 + 3] };
    *(half4*)(out + (size_t)(c0 + cl) * 4096 + k0 + r4) = p;
  }
}

// ============ 256^2 8-phase GEMM: C = A[M][K] * Bt[N][K]^T ============
// 512 threads = 8 waves (2 m x 4 n). LDS 128 KiB dynamic, double-buffered,
// K-tile (BK=64) split into two k-halves of 256 rows x 32 cols (16 KiB).
// T2 swizzle: 16B slot ^= (row>>1)&3 within 64B rows (both-sides: staged via
// pre-swizzled global source, read with same XOR).  One vmcnt(4) per K-tile.
// mode 1: QKV scatter epilogue; mode 2: fp32 row-major epilogue.

#define A_OFF(d, h) ((d) * 32768 + (h) * 16384)
#define B_OFF(d, h) (65536 + (d) * 32768 + (h) * 16384)

// stage one k-half (16 KiB): per wave 2 x global_load_lds of 1 KiB chunks.
#define STAGE(gbase, ldsoff, ktb)                                              \
  do {                                                                         \
    _Pragma("unroll") for (int i_ = 0; i_ < 2; ++i_) {                         \
      int c_ = w * 2 + i_;                                                     \
      int row_ = c_ * 16 + (lane >> 2);                                        \
      int ss_ = (lane & 3) ^ ((lane >> 3) & 3);                                \
      __builtin_amdgcn_global_load_lds(                                        \
          AS1((gbase) + (size_t)row_ * ldb + (ktb) + ss_ * 16),                \
          AS3(lds + (ldsoff) + c_ * 1024), 16, 0, 0);                          \
    }                                                                          \
  } while (0)

#define LDA(dst, d, ks, fm)                                                    \
  do {                                                                         \
    int r_ = wr * 128 + (fm) * 16 + (lane & 15);                               \
    int sl_ = (lane >> 4) ^ ((r_ >> 1) & 3);                                   \
    dst = *(const half8*)(lds + (d) * 32768 + (ks) * 16384 + r_ * 64 +         \
                          sl_ * 16);                                           \
  } while (0)

#define LDB(dst, d, ks, fn)                                                    \
  do {                                                                         \
    int r_ = wc * 64 + (fn) * 16 + (lane & 15);                                \
    int sl_ = (lane >> 4) ^ ((r_ >> 1) & 3);                                   \
    dst = *(const half8*)(lds + 65536 + (d) * 32768 + (ks) * 16384 +           \
                          r_ * 64 + sl_ * 16);                                 \
  } while (0)

#define BARRIER()                                                              \
  do {                                                                         \
    asm volatile("" ::: "memory");                                             \
    __builtin_amdgcn_s_barrier();                                              \
    asm volatile("" ::: "memory");                                             \
  } while (0)

#define MFMA16(mh)                                                             \
  do {                                                                         \
    __builtin_amdgcn_s_setprio(1);                                             \
    _Pragma("unroll") for (int mi_ = 0; mi_ < 4; ++mi_)                        \
        _Pragma("unroll") for (int ni_ = 0; ni_ < 4; ++ni_)                    \
            acc[(mh) * 4 + mi_][ni_] = __builtin_amdgcn_mfma_f32_16x16x32_f16( \
                af[mi_], bfr[ni_], acc[(mh) * 4 + mi_][ni_], 0, 0, 0);         \
    __builtin_amdgcn_s_setprio(0);                                             \
  } while (0)

__global__ __launch_bounds__(512, 2) void k_gemm256(
    const _Float16* __restrict__ A, const _Float16* __restrict__ Bt,
    void* __restrict__ outp, int M, int N, int K, int mode, int ntn, int nblk) {
  extern __shared__ __align__(16) char lds[];
  int tid = threadIdx.x, lane = tid & 63, w = tid >> 6;
  int wr = w >> 2, wc = w & 3;
  // T1: bijective XCD swizzle (nblk % 8 == 0)
  int bid = blockIdx.x;
  int sid = (bid & 7) * (nblk >> 3) + (bid >> 3);
  int mt = sid / ntn, nt = sid % ntn;
  int m0 = mt * 256, n0 = nt * 256;

  const char* Ab = (const char*)(A + (size_t)m0 * K);
  const char* Bb = (const char*)(Bt + (size_t)n0 * K);
  size_t ldb = (size_t)K * 2;

  f32x4 acc[8][4];
#pragma unroll
  for (int i = 0; i < 8; ++i)
#pragma unroll
    for (int j = 0; j < 4; ++j) acc[i][j] = (f32x4){0.f, 0.f, 0.f, 0.f};
  half8 af[4], bfr[4];

  int NT = K >> 6;
  // ---- prologue: tile0 all 4 halves, tile1 k0 halves ----
  STAGE(Ab, A_OFF(0, 0), 0);
  STAGE(Bb, B_OFF(0, 0), 0);
  STAGE(Ab, A_OFF(0, 1), 64);
  STAGE(Bb, B_OFF(0, 1), 64);
  STAGE(Ab, A_OFF(1, 0), 128);
  STAGE(Bb, B_OFF(1, 0), 128);
  asm volatile("s_waitcnt vmcnt(4)" ::: "memory");
  BARRIER();

  for (int k = 0; k < NT; ++k) {
    int d = k & 1, dn = d ^ 1;
    int ktb1 = (k + 1) << 7, ktb2 = (k + 2) << 7;
    bool s1 = (k + 1 < NT), s2 = (k + 2 < NT);
    // ---- ph0: ks0, mh0 ----
    LDB(bfr[0], d, 0, 0); LDB(bfr[1], d, 0, 1);
    LDB(bfr[2], d, 0, 2); LDB(bfr[3], d, 0, 3);
    LDA(af[0], d, 0, 0); LDA(af[1], d, 0, 1);
    LDA(af[2], d, 0, 2); LDA(af[3], d, 0, 3);
    if (s1) STAGE(Ab, A_OFF(dn, 1), ktb1 + 64);
    BARRIER();
    MFMA16(0);
    BARRIER();
    // ---- ph1: ks0, mh1 ----
    LDA(af[0], d, 0, 4); LDA(af[1], d, 0, 5);
    LDA(af[2], d, 0, 6); LDA(af[3], d, 0, 7);
    if (s1) STAGE(Bb, B_OFF(dn, 1), ktb1 + 64);
    BARRIER();
    MFMA16(1);
    BARRIER();
    // ---- ph2: ks1, mh0 ----
    LDB(bfr[0], d, 1, 0); LDB(bfr[1], d, 1, 1);
    LDB(bfr[2], d, 1, 2); LDB(bfr[3], d, 1, 3);
    LDA(af[0], d, 1, 0); LDA(af[1], d, 1, 1);
    LDA(af[2], d, 1, 2); LDA(af[3], d, 1, 3);
    if (s2) STAGE(Ab, A_OFF(d, 0), ktb2);
    BARRIER();
    MFMA16(0);
    BARRIER();
    // ---- ph3: ks1, mh1 (+ boundary vmcnt) ----
    LDA(af[0], d, 1, 4); LDA(af[1], d, 1, 5);
    LDA(af[2], d, 1, 6); LDA(af[3], d, 1, 7);
    if (s2) {
      STAGE(Bb, B_OFF(d, 0), ktb2);
      asm volatile("s_waitcnt vmcnt(4)" ::: "memory");
    } else {
      asm volatile("s_waitcnt vmcnt(0)" ::: "memory");
    }
    BARRIER();
    MFMA16(1);
    BARRIER();
  }

  // ---- epilogue ----
  if (mode == 2) {
    float* O = (float*)outp;
#pragma unroll
    for (int fm = 0; fm < 8; ++fm)
#pragma unroll
      for (int j = 0; j < 4; ++j) {
        int r = m0 + wr * 128 + fm * 16 + ((lane >> 4) << 2) + j;
        float* op = O + (size_t)r * N + n0 + wc * 64 + (lane & 15);
#pragma unroll
        for (int ni = 0; ni < 4; ++ni) op[ni * 16] = acc[fm][ni][j];
      }
  } else {
    _Float16* Q = (_Float16*)outp;
    _Float16* Kk = Q + 16777216;   // +32 MiB
    _Float16* Vt = Q + 33554432;   // +64 MiB
    int cb0 = n0 + wc * 64;        // 64-aligned column base
    int seg = cb0 >> 12;           // 0:q 1:k 2:v
    int h = (cb0 >> 7) & 31;
    int dbase = cb0 & 127;
    if (seg < 2) {
      _Float16* Obuf = (seg == 0) ? Q : Kk;
#pragma unroll
      for (int fm = 0; fm < 8; ++fm) {
        int t0 = m0 + wr * 128 + fm * 16 + ((lane >> 4) << 2);
        int bb = t0 >> 10, s0 = t0 & 1023;
        size_t base = ((size_t)bb * 32 + h) * 1024;
#pragma unroll
        for (int j = 0; j < 4; ++j)
#pragma unroll
          for (int ni = 0; ni < 4; ++ni)
            Obuf[(base + s0 + j) * 128 + dbase + ni * 16 + (lane & 15)] =
                (_Float16)acc[fm][ni][j];
      }
    } else {
#pragma unroll
      for (int fm = 0; fm < 8; ++fm) {
        int t0 = m0 + wr * 128 + fm * 16 + ((lane >> 4) << 2);
        int bb = t0 >> 10, s0 = t0 & 1023;
#pragma unroll
        for (int ni = 0; ni < 4; ++ni) {
          int dd = dbase + ni * 16 + (lane & 15);
          half4 p = { (_Float16)acc[fm][ni][0], (_Float16)acc[fm][ni][1],
                      (_Float16)acc[fm][ni][2], (_Float16)acc[fm][ni][3] };
          *(half4*)(Vt + (((size_t)bb * 32 + h) * 128 + dd) * 1024 + s0) = p;
        }
      }
    }
  }
}

// ---------------- causal flash attention (unchanged r3 baseline) ----------------
__global__ __launch_bounds__(256) void k_attn(const _Float16* __restrict__ Qb,
                                              const _Float16* __restrict__ Kb,
                                              const _Float16* __restrict__ Vtb,
                                              _Float16* __restrict__ outp) {
  __shared__ __align__(16) _Float16 sK[64][152];
  __shared__ __align__(16) _Float16 sV[128][72];
  __shared__ __align__(16) _Float16 sP[4][16][72];
  const float SCL = 0.10411834905624762f;  // 192^-0.5 * log2(e)
  int tid = threadIdx.x;
  int lane = tid & 63;
  int w = tid >> 6;
  int qt = blockIdx.x;
  int h = blockIdx.y;
  int b = blockIdx.z;
  int q0 = qt * 64;
  size_t bh = (size_t)b * 32 + h;
  const _Float16* Qp = Qb + bh * (1024 * 128);
  const _Float16* Kp = Kb + bh * (1024 * 128);
  const _Float16* Vp = Vtb + bh * (128 * 1024);

  half8 aQ[4];
  {
    const _Float16* qr = Qp + (size_t)(q0 + w * 16 + (lane & 15)) * 128 + ((lane >> 4) << 3);
#pragma unroll
    for (int ks = 0; ks < 4; ++ks) aQ[ks] = *(const half8*)(qr + ks * 32);
  }
  f32x4 accO[8];
#pragma unroll
  for (int g = 0; g < 8; ++g) accO[g] = (f32x4){0.f, 0.f, 0.f, 0.f};
  float m_r[4] = { -__builtin_inff(), -__builtin_inff(), -__builtin_inff(), -__builtin_inff() };
  float l_r[4] = { 0.f, 0.f, 0.f, 0.f };

  int ntile = qt + 1;
  int qrb = q0 + w * 16 + ((lane >> 4) << 2);
  for (int kt = 0; kt < ntile; ++kt) {
    int kv0 = kt * 64;
#pragma unroll
    for (int i = 0; i < 4; ++i) {
      int idx = tid + i * 256;
      int r = idx >> 4;
      int cb = (idx & 15) << 3;
      *(int4*)&sK[r][cb] = *(const int4*)(Kp + (size_t)(kv0 + r) * 128 + cb);
    }
#pragma unroll
    for (int i = 0; i < 4; ++i) {
      int idx = tid + i * 256;
      int r = idx >> 3;
      int cb = (idx & 7) << 3;
      *(int4*)&sV[r][cb] = *(const int4*)(Vp + (size_t)r * 1024 + kv0 + cb);
    }
    __syncthreads();
    f32x4 sc[4];
#pragma unroll
    for (int g = 0; g < 4; ++g) {
      f32x4 c = (f32x4){0.f, 0.f, 0.f, 0.f};
#pragma unroll
      for (int ks = 0; ks < 4; ++ks) {
        half8 bk = *(const half8*)&sK[g * 16 + (lane & 15)][ks * 32 + ((lane >> 4) << 3)];
        c = __builtin_amdgcn_mfma_f32_16x16x32_f16(aQ[ks], bk, c, 0, 0, 0);
      }
      sc[g] = c;
    }
    bool diag = (kt == ntile - 1);
    float sv[4][4];
#pragma unroll
    for (int g = 0; g < 4; ++g) {
      int kvc = kv0 + g * 16 + (lane & 15);
#pragma unroll
      for (int j = 0; j < 4; ++j) {
        float s = sc[g][j] * SCL;
        if (diag && kvc > qrb + j) s = -__builtin_inff();
        sv[j][g] = s;
      }
    }
#pragma unroll
    for (int j = 0; j < 4; ++j) {
      float mx = fmaxf(fmaxf(sv[j][0], sv[j][1]), fmaxf(sv[j][2], sv[j][3]));
      mx = fmaxf(mx, __shfl_xor(mx, 1));
      mx = fmaxf(mx, __shfl_xor(mx, 2));
      mx = fmaxf(mx, __shfl_xor(mx, 4));
      mx = fmaxf(mx, __shfl_xor(mx, 8));
      float mnew = fmaxf(m_r[j], mx);
      float corr = exp2f(m_r[j] - mnew);
      m_r[j] = mnew;
      float rs = 0.f;
#pragma unroll
      for (int g = 0; g < 4; ++g) {
        float p = exp2f(sv[j][g] - mnew);
        sv[j][g] = p;
        rs += p;
      }
      rs += __shfl_xor(rs, 1);
      rs += __shfl_xor(rs, 2);
      rs += __shfl_xor(rs, 4);
      rs += __shfl_xor(rs, 8);
      l_r[j] = l_r[j] * corr + rs;
#pragma unroll
      for (int g2 = 0; g2 < 8; ++g2) accO[g2][j] *= corr;
    }
#pragma unroll
    for (int j = 0; j < 4; ++j)
#pragma unroll
      for (int g = 0; g < 4; ++g)
        sP[w][((lane >> 4) << 2) + j][g * 16 + (lane & 15)] = (_Float16)sv[j][g];
    __syncthreads();
#pragma unroll
    for (int ks = 0; ks < 2; ++ks) {
      half8 ap = *(const half8*)&sP[w][lane & 15][ks * 32 + ((lane >> 4) << 3)];
#pragma unroll
      for (int g2 = 0; g2 < 8; ++g2) {
        half8 bv = *(const half8*)&sV[g2 * 16 + (lane & 15)][ks * 32 + ((lane >> 4) << 3)];
        accO[g2] = __builtin_amdgcn_mfma_f32_16x16x32_f16(ap, bv, accO[g2], 0, 0, 0);
      }
    }
    __syncthreads();
  }
  float inv[4];
#pragma unroll
  for (int j = 0; j < 4; ++j) inv[j] = 1.f / l_r[j];
#pragma unroll
  for (int j = 0; j < 4; ++j) {
    size_t rb = ((size_t)b * 1024 + qrb + j) * 4096 + (size_t)h * 128 + (lane & 15);
#pragma unroll
    for (int g2 = 0; g2 < 8; ++g2)
      outp[rb + g2 * 16] = (_Float16)(accO[g2][j] * inv[j]);
  }
}

// ---------------- launch ----------------
extern "C" void kernel_launch(void* const* d_in, const int* in_sizes, int n_in,
                              void* d_out, int out_size, void* d_ws, size_t ws_size,
                              hipStream_t stream) {
  const float* hs  = (const float*)d_in[0];
  const float* wq  = (const float*)d_in[1];
  const float* wkv = (const float*)d_in[2];
  const float* wo  = (const float*)d_in[3];
  char* ws = (char*)d_ws;

  const size_t OFF_HS    = 0;           // 32 MiB (later aliased by woT)
  const size_t OFF_WQKVT = 33554432;    // 96 MiB (later aliased by attn out)
  const size_t OFF_Q     = 134217728;   // 96 MiB (Q | K | Vt)
  const size_t OFF_ATTN  = OFF_WQKVT;
  const size_t OFF_WOT   = OFF_HS;

  _Float16* hs16   = (_Float16*)(ws + OFF_HS);
  _Float16* wqkvT  = (_Float16*)(ws + OFF_WQKVT);
  _Float16* qkv    = (_Float16*)(ws + OFF_Q);
  _Float16* attn   = (_Float16*)(ws + OFF_ATTN);
  _Float16* woT    = (_Float16*)(ws + OFF_WOT);

  hipFuncSetAttribute((const void*)k_gemm256,
                      hipFuncAttributeMaxDynamicSharedMemorySize, 131072);

  // 1) hs -> f16
  k_convert<<<8192, 256, 0, stream>>>(hs, hs16);
  // 2) weights -> B^T f16 (rope columns dropped)
  k_tc_qkv<<<dim3(64, 192), 256, 0, stream>>>(wq, wkv, wqkvT);
  // 3) QKV projection GEMM (256^2 8-phase), epilogue scatters Q/K/V^T
  k_gemm256<<<768, 512, 131072, stream>>>(hs16, wqkvT, (void*)qkv,
                                          4096, 12288, 4096, 1, 48, 768);
  // 4) wo -> B^T f16 (hs16 slot is dead now)
  k_tc_wo<<<dim3(64, 64), 256, 0, stream>>>(wo, woT);
  // 5) causal flash attention -> attn [t][4096] f16 (wqkvT slot is dead now)
  k_attn<<<dim3(16, 32, 4), 256, 0, stream>>>(qkv, qkv + 16777216, qkv + 33554432, attn);
  // 6) output projection (256^2 8-phase) -> fp32 d_out
  k_gemm256<<<256, 512, 131072, stream>>>(attn, woT, d_out,
                                          4096, 4096, 4096, 2, 16, 256);
}